// Round 2
// baseline (1760.887 us; speedup 1.0000x reference)
//
#include <hip/hip_runtime.h>
#include <hip/hip_bf16.h>

#define NEG_SLOPE 0.2f

__device__ __forceinline__ float waveSum(float v){
    #pragma unroll
    for (int off = 32; off > 0; off >>= 1) v += __shfl_xor(v, off, 64);
    return v;
}

// ---------------- CSR build ----------------

__global__ void edge_count(const int* __restrict__ src, const int* __restrict__ dst,
                           int E, int* __restrict__ counts){
    int e = blockIdx.x * blockDim.x + threadIdx.x;
    if (e >= E) return;
    int s = src[e], d = dst[e];
    if (s != d) atomicAdd(&counts[d], 1);
}

__global__ void scan_block(const int* __restrict__ counts, int* __restrict__ offsets,
                           int* __restrict__ blockSums, int N){
    __shared__ int sh[256];
    int t = threadIdx.x;
    int i = blockIdx.x * 256 + t;
    int v = (i < N) ? counts[i] : 0;
    sh[t] = v; __syncthreads();
    for (int off = 1; off < 256; off <<= 1){
        int x = (t >= off) ? sh[t - off] : 0;
        __syncthreads();
        sh[t] += x;
        __syncthreads();
    }
    if (i < N) offsets[i] = sh[t] - v;           // exclusive
    if (t == 255) blockSums[blockIdx.x] = sh[255];
}

__global__ void scan_sums(int* __restrict__ blockSums, int nb){
    __shared__ int sh[256];
    int t = threadIdx.x;
    int v = (t < nb) ? blockSums[t] : 0;
    sh[t] = v; __syncthreads();
    for (int off = 1; off < 256; off <<= 1){
        int x = (t >= off) ? sh[t - off] : 0;
        __syncthreads();
        sh[t] += x;
        __syncthreads();
    }
    if (t < nb) blockSums[t] = sh[t] - v;        // exclusive
}

__global__ void scan_add(int* __restrict__ offsets, const int* __restrict__ blockSums, int N){
    int i = blockIdx.x * 256 + threadIdx.x;
    if (i < N) offsets[i] += blockSums[blockIdx.x];
}

__global__ void copy_int(const int* __restrict__ a, int* __restrict__ b, int N){
    int i = blockIdx.x * blockDim.x + threadIdx.x;
    if (i < N) b[i] = a[i];
}

__global__ void edge_scatter(const int* __restrict__ src, const int* __restrict__ dst,
                             int E, int* __restrict__ cursor, int* __restrict__ edge_src){
    int e = blockIdx.x * blockDim.x + threadIdx.x;
    if (e >= E) return;
    int s = src[e], d = dst[e];
    if (s != d){
        int pos = atomicAdd(&cursor[d], 1);
        edge_src[pos] = s;
    }
}

// ---------------- dual linear: xl = in@Wl+bl, xr = in@Wr+br ----------------
// grid = N rows; block = 2*HC threads; dynamic LDS = K floats.
__global__ void dual_linear(const float* __restrict__ in,
                            const float* __restrict__ Wl, const float* __restrict__ bl,
                            const float* __restrict__ Wr, const float* __restrict__ br,
                            float* __restrict__ xl, float* __restrict__ xr,
                            int K, int HC){
    extern __shared__ float xs[];
    int row = blockIdx.x;
    int tid = threadIdx.x;
    const float* inp = in + (size_t)row * K;
    for (int k = tid; k < K; k += blockDim.x) xs[k] = inp[k];
    __syncthreads();
    bool left = tid < HC;
    int col = left ? tid : tid - HC;
    const float* W = left ? Wl : Wr;
    const float* bb = left ? bl : br;
    float acc = bb[col];
    for (int k = 0; k < K; ++k) acc += xs[k] * W[k * HC + col];
    float* outp = left ? xl : xr;
    outp[(size_t)row * HC + col] = acc;
}

// ---------------- GATv2 aggregation (online softmax), one wave per (node[,head]) ----------------
template<int H, bool MEAN>
__global__ __launch_bounds__(256)
void gatv2_agg(const float* __restrict__ xl, const float* __restrict__ xr,
               const float* __restrict__ att, const float* __restrict__ bias,
               const int* __restrict__ offsets, const int* __restrict__ counts,
               const int* __restrict__ edge_src,
               float* __restrict__ hout, int N){
    const int HC = H * 64;
    int wid  = (blockIdx.x * blockDim.x + threadIdx.x) >> 6;
    int lane = threadIdx.x & 63;
    int n, h0, h1;
    if (MEAN){ n = wid; h0 = 0; h1 = H; }
    else     { n = wid / H; h0 = wid % H; h1 = h0 + 1; }
    if (n >= N) return;
    int rs = offsets[n];
    int re = rs + counts[n];
    float result = 0.f;
    for (int h = h0; h < h1; ++h){
        float attv = att[h * 64 + lane];
        size_t base = (size_t)n * HC + h * 64 + lane;
        float xrv = xr[base];
        float xlv = xl[base];
        // implicit self loop first
        float t0 = xrv + xlv; t0 = t0 > 0.f ? t0 : NEG_SLOPE * t0;
        float m = waveSum(t0 * attv);
        float denom = 1.f;
        float acc = xlv;
        for (int i = rs; i < re; ++i){
            int s = edge_src[i];
            float xv = xl[(size_t)s * HC + h * 64 + lane];
            float t = xrv + xv; t = t > 0.f ? t : NEG_SLOPE * t;
            float lg = waveSum(t * attv);
            if (lg <= m){
                float p = __expf(lg - m);
                denom += p; acc += p * xv;
            } else {
                float sc = __expf(m - lg);
                denom = denom * sc + 1.f;
                acc = acc * sc + xv;
                m = lg;
            }
        }
        result += acc / denom;
    }
    if (MEAN){
        result *= (1.f / H);
        float o = result + bias[lane];
        hout[(size_t)n * 64 + lane] = o > 0.f ? o : 0.f;
    } else {
        float o = result + bias[h0 * 64 + lane];
        hout[(size_t)n * HC + h0 * 64 + lane] = o > 0.f ? o : 0.f;
    }
}

// ---------------- pooling ----------------
__global__ void pool_kernel(const float* __restrict__ h, const int* __restrict__ batch,
                            int N, float* __restrict__ gmx, float* __restrict__ gsum,
                            int* __restrict__ gcnt){
    int i = blockIdx.x * blockDim.x + threadIdx.x;
    if (i >= N * 64) return;
    int n = i >> 6, c = i & 63;
    int g = batch[n];
    float v = h[i];
    atomicMax((int*)&gmx[g * 64 + c], __float_as_int(v));  // v >= 0 after relu
    atomicAdd(&gsum[g * 64 + c], v);
    if (c == 0) atomicAdd(&gcnt[g], 1);
}

__global__ void final_linear(const float* __restrict__ gmx, const float* __restrict__ gsum,
                             const int* __restrict__ gcnt,
                             const float* __restrict__ Wout, const float* __restrict__ bout,
                             float* __restrict__ out){
    int t = threadIdx.x;             // one block, 640 threads
    if (t >= 640) return;
    int g = t / 10, oc = t % 10;
    float cnt = (float)max(gcnt[g], 1);
    float acc = bout[oc];
    for (int k = 0; k < 64; ++k)  acc += gmx[g * 64 + k] * Wout[k * 10 + oc];
    for (int k = 0; k < 64; ++k)  acc += (gsum[g * 64 + k] / cnt) * Wout[(64 + k) * 10 + oc];
    out[g * 10 + oc] = acc;
}

// ---------------- launch ----------------
extern "C" void kernel_launch(void* const* d_in, const int* in_sizes, int n_in,
                              void* d_out, int out_size, void* d_ws, size_t ws_size,
                              hipStream_t stream){
    const int N = 50000, E = 800000, B = 64;
    const float* x    = (const float*)d_in[0];
    const int*  ei    = (const int*)d_in[1];
    const int*  batch = (const int*)d_in[2];
    const float *Wl0=(const float*)d_in[3],  *bl0=(const float*)d_in[4],
                *Wr0=(const float*)d_in[5],  *br0=(const float*)d_in[6],
                *att0=(const float*)d_in[7], *bias0=(const float*)d_in[8];
    const float *Wl1=(const float*)d_in[9],  *bl1=(const float*)d_in[10],
                *Wr1=(const float*)d_in[11], *br1=(const float*)d_in[12],
                *att1=(const float*)d_in[13],*bias1=(const float*)d_in[14];
    const float *Wl2=(const float*)d_in[15], *bl2=(const float*)d_in[16],
                *Wr2=(const float*)d_in[17], *br2=(const float*)d_in[18],
                *att2=(const float*)d_in[19],*bias2=(const float*)d_in[20];
    const float *Wout=(const float*)d_in[21],*bout=(const float*)d_in[22];

    const int* srcA = ei;
    const int* dstA = ei + E;

    char* p = (char*)d_ws;
    auto alloc = [&](size_t bytes)->void*{ void* r = (void*)p; p += (bytes + 255) & ~(size_t)255; return r; };
    float* bufA   = (float*)alloc((size_t)N * 192 * 4);
    float* bufB   = (float*)alloc((size_t)N * 192 * 4);
    float* bufC   = (float*)alloc((size_t)N * 192 * 4);
    int* counts   = (int*)alloc((size_t)N * 4);
    int* offsets  = (int*)alloc((size_t)N * 4);
    int* cursor   = (int*)alloc((size_t)N * 4);
    int* blockSums= (int*)alloc(256 * 4);
    int* edge_src = (int*)alloc((size_t)E * 4);
    float* gmx    = (float*)alloc((size_t)B * 64 * 4);
    float* gsum   = (float*)alloc((size_t)B * 64 * 4);
    int* gcnt     = (int*)alloc((size_t)B * 4);

    // CSR build (reused by all 3 layers)
    hipMemsetAsync(counts, 0, (size_t)N * 4, stream);
    int eb = (E + 255) / 256;
    int nb = (N + 255) / 256;
    edge_count<<<eb, 256, 0, stream>>>(srcA, dstA, E, counts);
    scan_block<<<nb, 256, 0, stream>>>(counts, offsets, blockSums, N);
    scan_sums<<<1, 256, 0, stream>>>(blockSums, nb);
    scan_add<<<nb, 256, 0, stream>>>(offsets, blockSums, N);
    copy_int<<<nb, 256, 0, stream>>>(offsets, cursor, N);
    edge_scatter<<<eb, 256, 0, stream>>>(srcA, dstA, E, cursor, edge_src);

    // layer 0: 32 -> 192 (H=3, C=64), concat
    dual_linear<<<N, 384, 32 * 4, stream>>>(x, Wl0, bl0, Wr0, br0, bufB, bufC, 32, 192);
    gatv2_agg<3,false><<<(N * 3 + 3) / 4, 256, 0, stream>>>(bufB, bufC, att0, bias0, offsets, counts, edge_src, bufA, N);

    // layer 1: 192 -> 128 (H=2), concat
    dual_linear<<<N, 256, 192 * 4, stream>>>(bufA, Wl1, bl1, Wr1, br1, bufB, bufC, 192, 128);
    gatv2_agg<2,false><<<(N * 2 + 3) / 4, 256, 0, stream>>>(bufB, bufC, att1, bias1, offsets, counts, edge_src, bufA, N);

    // layer 2: 128 -> 128 (H=2), mean over heads -> 64
    dual_linear<<<N, 256, 128 * 4, stream>>>(bufA, Wl2, bl2, Wr2, br2, bufB, bufC, 128, 128);
    gatv2_agg<2,true ><<<(N + 3) / 4, 256, 0, stream>>>(bufB, bufC, att2, bias2, offsets, counts, edge_src, bufA, N);

    // pooling + output linear
    hipMemsetAsync(gmx,  0, (size_t)B * 64 * 4, stream);
    hipMemsetAsync(gsum, 0, (size_t)B * 64 * 4, stream);
    hipMemsetAsync(gcnt, 0, (size_t)B * 4, stream);
    pool_kernel<<<(N * 64 + 255) / 256, 256, 0, stream>>>(bufA, batch, N, gmx, gsum, gcnt);
    final_linear<<<1, 640, 0, stream>>>(gmx, gsum, gcnt, Wout, bout, (float*)d_out);
}

// Round 3
// 895.279 us; speedup vs baseline: 1.9669x; 1.9669x over previous
//
#include <hip/hip_runtime.h>
#include <hip/hip_bf16.h>
#include <math.h>

#define NEG_SLOPE 0.2f

__device__ __forceinline__ void fma4(float4& a, const float4 w, const float s){
    a.x += w.x * s; a.y += w.y * s; a.z += w.z * s; a.w += w.w * s;
}

// ---------------- CSR build ----------------

__global__ void edge_count(const int* __restrict__ src, const int* __restrict__ dst,
                           int E, int* __restrict__ counts){
    int e = blockIdx.x * blockDim.x + threadIdx.x;
    if (e >= E) return;
    int s = src[e], d = dst[e];
    if (s != d) atomicAdd(&counts[d], 1);
}

__global__ void scan_block(const int* __restrict__ counts, int* __restrict__ offsets,
                           int* __restrict__ blockSums, int N){
    __shared__ int sh[256];
    int t = threadIdx.x;
    int i = blockIdx.x * 256 + t;
    int v = (i < N) ? counts[i] : 0;
    sh[t] = v; __syncthreads();
    for (int off = 1; off < 256; off <<= 1){
        int x = (t >= off) ? sh[t - off] : 0;
        __syncthreads();
        sh[t] += x;
        __syncthreads();
    }
    if (i < N) offsets[i] = sh[t] - v;           // exclusive
    if (t == 255) blockSums[blockIdx.x] = sh[255];
}

__global__ void scan_sums(int* __restrict__ blockSums, int nb){
    __shared__ int sh[256];
    int t = threadIdx.x;
    int v = (t < nb) ? blockSums[t] : 0;
    sh[t] = v; __syncthreads();
    for (int off = 1; off < 256; off <<= 1){
        int x = (t >= off) ? sh[t - off] : 0;
        __syncthreads();
        sh[t] += x;
        __syncthreads();
    }
    if (t < nb) blockSums[t] = sh[t] - v;        // exclusive
}

__global__ void scan_add(int* __restrict__ offsets, const int* __restrict__ blockSums, int N){
    int i = blockIdx.x * 256 + threadIdx.x;
    if (i < N) offsets[i] += blockSums[blockIdx.x];
}

__global__ void copy_int(const int* __restrict__ a, int* __restrict__ b, int N){
    int i = blockIdx.x * blockDim.x + threadIdx.x;
    if (i < N) b[i] = a[i];
}

__global__ void edge_scatter(const int* __restrict__ src, const int* __restrict__ dst,
                             int E, int* __restrict__ cursor, int* __restrict__ edge_src){
    int e = blockIdx.x * blockDim.x + threadIdx.x;
    if (e >= E) return;
    int s = src[e], d = dst[e];
    if (s != d){
        int pos = atomicAdd(&cursor[d], 1);
        edge_src[pos] = s;
    }
}

// ---------------- dual linear (tiled, register-blocked) ----------------
// Computes [xl | xr] = in @ [Wl | Wr] + [bl | br].
// Block: 32 rows x HC2 cols. Thread: 4 cols x 8 rows (32 f32 accumulators).
// x-tile transposed in LDS (stride 36 floats -> 16B-aligned b128 reads,
// wave-uniform broadcast => conflict-free).
template<int K, int HC2, int NT>
__global__ __launch_bounds__(NT)
void dual_linear_t(const float* __restrict__ in,
                   const float* __restrict__ Wl, const float* __restrict__ bl,
                   const float* __restrict__ Wr, const float* __restrict__ br,
                   float* __restrict__ xl, float* __restrict__ xr, int N){
    constexpr int HC = HC2 / 2;
    constexpr int CG = HC2 / 4;        // col groups of 4
    constexpr int STR = 36;            // LDS stride (floats), 144B = 16B-aligned
    __shared__ __align__(16) float xsT[K * STR];
    const int tid = threadIdx.x;
    const int row0 = blockIdx.x * 32;

    #pragma unroll 4
    for (int r = 0; r < 32; ++r){
        int gr = row0 + r; if (gr > N - 1) gr = N - 1;
        const float* ip = in + (size_t)gr * K;
        for (int k = tid; k < K; k += NT) xsT[k * STR + r] = ip[k];
    }
    __syncthreads();

    const int cg = tid % CG, rg = tid / CG;
    const int c4 = cg * 4, r8 = rg * 8;
    const bool left = c4 < HC;
    const float* Wb = left ? (Wl + c4) : (Wr + (c4 - HC));
    const float* bb = left ? (bl + c4) : (br + (c4 - HC));
    const float4 bv = *(const float4*)bb;
    float4 acc[8];
    #pragma unroll
    for (int r = 0; r < 8; ++r) acc[r] = bv;

    const float* wp = Wb;
    const float* xp = &xsT[r8];
    #pragma unroll 4
    for (int k = 0; k < K; ++k){
        float4 wv = *(const float4*)wp;  wp += HC;
        float4 xa = *(const float4*)xp;
        float4 xb = *(const float4*)(xp + 4);
        xp += STR;
        fma4(acc[0], wv, xa.x); fma4(acc[1], wv, xa.y);
        fma4(acc[2], wv, xa.z); fma4(acc[3], wv, xa.w);
        fma4(acc[4], wv, xb.x); fma4(acc[5], wv, xb.y);
        fma4(acc[6], wv, xb.z); fma4(acc[7], wv, xb.w);
    }

    float* ob = left ? (xl + c4) : (xr + (c4 - HC));
    #pragma unroll
    for (int r = 0; r < 8; ++r){
        int row = row0 + r8 + r;
        if (row < N) *(float4*)&ob[(size_t)row * HC] = acc[r];
    }
}

// ---------------- GATv2 aggregation ----------------
// One wave per (node [, head]). Wave = 4 groups x 16 lanes; each group runs an
// independent online softmax over a strided quarter of {self} U edges, channels
// held as float4 per lane (16 lanes x 4 = 64 channels). States merged at the
// end via shfl_xor(16/32) flash-style combine.
template<int H, bool MEAN>
__global__ __launch_bounds__(256)
void gatv2_agg(const float* __restrict__ xl, const float* __restrict__ xr,
               const float* __restrict__ att, const float* __restrict__ bias,
               const int* __restrict__ offsets, const int* __restrict__ counts,
               const int* __restrict__ edge_src,
               float* __restrict__ hout, int N){
    const int HC = H * 64;
    int wid  = (blockIdx.x * 256 + threadIdx.x) >> 6;
    int lane = threadIdx.x & 63;
    int g = lane >> 4, sl = lane & 15, cb = sl * 4;
    int n, h0, h1;
    if (MEAN){ n = wid; h0 = 0; h1 = H; }
    else     { n = wid / H; h0 = wid - n * H; h1 = h0 + 1; }
    if (n >= N) return;
    const int rs = offsets[n];
    const int total = counts[n] + 1;     // + implicit self loop (virtual idx 0)

    float ox = 0.f, oy = 0.f, oz = 0.f, ow = 0.f;
    for (int h = h0; h < h1; ++h){
        const float4 a4 = *(const float4*)&att[h * 64 + cb];
        const float4 q4 = *(const float4*)&xr[(size_t)n * HC + h * 64 + cb];
        const float* XT = xl + h * 64 + cb;
        float m = -INFINITY, den = 0.f;
        float ax = 0.f, ay = 0.f, az = 0.f, aw = 0.f;
        for (int j = g; j < total; j += 4){
            int s = (j == 0) ? n : edge_src[rs + j - 1];
            float4 xv = *(const float4*)&XT[(size_t)s * HC];
            float t0 = q4.x + xv.x, t1 = q4.y + xv.y;
            float t2 = q4.z + xv.z, t3 = q4.w + xv.w;
            t0 = t0 > 0.f ? t0 : NEG_SLOPE * t0;
            t1 = t1 > 0.f ? t1 : NEG_SLOPE * t1;
            t2 = t2 > 0.f ? t2 : NEG_SLOPE * t2;
            t3 = t3 > 0.f ? t3 : NEG_SLOPE * t3;
            float p = a4.x * t0 + a4.y * t1 + a4.z * t2 + a4.w * t3;
            p += __shfl_xor(p, 1, 64);
            p += __shfl_xor(p, 2, 64);
            p += __shfl_xor(p, 4, 64);
            p += __shfl_xor(p, 8, 64);
            float Mn = fmaxf(m, p);           // p finite -> Mn finite
            float ea = __expf(m - Mn);        // first iter: exp(-inf)=0
            float eb = __expf(p - Mn);
            den = den * ea + eb;
            ax = ax * ea + eb * xv.x; ay = ay * ea + eb * xv.y;
            az = az * ea + eb * xv.z; aw = aw * ea + eb * xv.w;
            m = Mn;
        }
        // merge the 4 group states (flash combine) across lane-bits 4,5
        #pragma unroll
        for (int off = 16; off <= 32; off <<= 1){
            float mo  = __shfl_xor(m,  off, 64);
            float dno = __shfl_xor(den, off, 64);
            float bx = __shfl_xor(ax, off, 64), by = __shfl_xor(ay, off, 64);
            float bz = __shfl_xor(az, off, 64), bw = __shfl_xor(aw, off, 64);
            float Mn = fmaxf(m, mo);
            float sa = (m  == -INFINITY) ? 0.f : __expf(m  - Mn);
            float sb = (mo == -INFINITY) ? 0.f : __expf(mo - Mn);
            den = den * sa + dno * sb;
            ax = ax * sa + bx * sb; ay = ay * sa + by * sb;
            az = az * sa + bz * sb; aw = aw * sa + bw * sb;
            m = Mn;
        }
        float inv = 1.f / den;                // self loop guarantees den > 0
        ox += ax * inv; oy += ay * inv; oz += az * inv; ow += aw * inv;
    }
    if (lane < 16){
        float4 o;
        if (MEAN){
            const float s = 1.f / H;
            const float4 bv = *(const float4*)&bias[cb];
            o.x = fmaxf(ox * s + bv.x, 0.f);
            o.y = fmaxf(oy * s + bv.y, 0.f);
            o.z = fmaxf(oz * s + bv.z, 0.f);
            o.w = fmaxf(ow * s + bv.w, 0.f);
            *(float4*)&hout[(size_t)n * 64 + cb] = o;
        } else {
            const float4 bv = *(const float4*)&bias[h0 * 64 + cb];
            o.x = fmaxf(ox + bv.x, 0.f);
            o.y = fmaxf(oy + bv.y, 0.f);
            o.z = fmaxf(oz + bv.z, 0.f);
            o.w = fmaxf(ow + bv.w, 0.f);
            *(float4*)&hout[(size_t)n * HC + h0 * 64 + cb] = o;
        }
    }
}

// ---------------- pooling ----------------
__global__ void pool_kernel(const float* __restrict__ h, const int* __restrict__ batch,
                            int N, float* __restrict__ gmx, float* __restrict__ gsum,
                            int* __restrict__ gcnt){
    int i = blockIdx.x * blockDim.x + threadIdx.x;
    if (i >= N * 64) return;
    int n = i >> 6, c = i & 63;
    int g = batch[n];
    float v = h[i];
    atomicMax((int*)&gmx[g * 64 + c], __float_as_int(v));  // v >= 0 after relu
    atomicAdd(&gsum[g * 64 + c], v);
    if (c == 0) atomicAdd(&gcnt[g], 1);
}

__global__ void final_linear(const float* __restrict__ gmx, const float* __restrict__ gsum,
                             const int* __restrict__ gcnt,
                             const float* __restrict__ Wout, const float* __restrict__ bout,
                             float* __restrict__ out){
    int t = threadIdx.x;             // one block, 640 threads
    if (t >= 640) return;
    int g = t / 10, oc = t % 10;
    float cnt = (float)max(gcnt[g], 1);
    float acc = bout[oc];
    for (int k = 0; k < 64; ++k)  acc += gmx[g * 64 + k] * Wout[k * 10 + oc];
    for (int k = 0; k < 64; ++k)  acc += (gsum[g * 64 + k] / cnt) * Wout[(64 + k) * 10 + oc];
    out[g * 10 + oc] = acc;
}

// ---------------- launch ----------------
extern "C" void kernel_launch(void* const* d_in, const int* in_sizes, int n_in,
                              void* d_out, int out_size, void* d_ws, size_t ws_size,
                              hipStream_t stream){
    const int N = 50000, E = 800000, B = 64;
    const float* x    = (const float*)d_in[0];
    const int*  ei    = (const int*)d_in[1];
    const int*  batch = (const int*)d_in[2];
    const float *Wl0=(const float*)d_in[3],  *bl0=(const float*)d_in[4],
                *Wr0=(const float*)d_in[5],  *br0=(const float*)d_in[6],
                *att0=(const float*)d_in[7], *bias0=(const float*)d_in[8];
    const float *Wl1=(const float*)d_in[9],  *bl1=(const float*)d_in[10],
                *Wr1=(const float*)d_in[11], *br1=(const float*)d_in[12],
                *att1=(const float*)d_in[13],*bias1=(const float*)d_in[14];
    const float *Wl2=(const float*)d_in[15], *bl2=(const float*)d_in[16],
                *Wr2=(const float*)d_in[17], *br2=(const float*)d_in[18],
                *att2=(const float*)d_in[19],*bias2=(const float*)d_in[20];
    const float *Wout=(const float*)d_in[21],*bout=(const float*)d_in[22];

    const int* srcA = ei;
    const int* dstA = ei + E;

    char* p = (char*)d_ws;
    auto alloc = [&](size_t bytes)->void*{ void* r = (void*)p; p += (bytes + 255) & ~(size_t)255; return r; };
    float* bufA   = (float*)alloc((size_t)N * 192 * 4);
    float* bufB   = (float*)alloc((size_t)N * 192 * 4);
    float* bufC   = (float*)alloc((size_t)N * 192 * 4);
    int* counts   = (int*)alloc((size_t)N * 4);
    int* offsets  = (int*)alloc((size_t)N * 4);
    int* cursor   = (int*)alloc((size_t)N * 4);
    int* blockSums= (int*)alloc(256 * 4);
    int* edge_src = (int*)alloc((size_t)E * 4);
    float* gmx    = (float*)alloc((size_t)B * 64 * 4);
    float* gsum   = (float*)alloc((size_t)B * 64 * 4);
    int* gcnt     = (int*)alloc((size_t)B * 4);

    // CSR build (reused by all 3 layers)
    hipMemsetAsync(counts, 0, (size_t)N * 4, stream);
    int eb = (E + 255) / 256;
    int nb = (N + 255) / 256;
    edge_count<<<eb, 256, 0, stream>>>(srcA, dstA, E, counts);
    scan_block<<<nb, 256, 0, stream>>>(counts, offsets, blockSums, N);
    scan_sums<<<1, 256, 0, stream>>>(blockSums, nb);
    scan_add<<<nb, 256, 0, stream>>>(offsets, blockSums, N);
    copy_int<<<nb, 256, 0, stream>>>(offsets, cursor, N);
    edge_scatter<<<eb, 256, 0, stream>>>(srcA, dstA, E, cursor, edge_src);

    const int rb = (N + 31) / 32;   // row-tile blocks for linears

    // layer 0: 32 -> 192 (H=3, C=64), concat
    dual_linear_t<32, 384, 384><<<rb, 384, 0, stream>>>(x, Wl0, bl0, Wr0, br0, bufB, bufC, N);
    gatv2_agg<3,false><<<(N * 3 + 3) / 4, 256, 0, stream>>>(bufB, bufC, att0, bias0, offsets, counts, edge_src, bufA, N);

    // layer 1: 192 -> 128 (H=2), concat
    dual_linear_t<192, 256, 256><<<rb, 256, 0, stream>>>(bufA, Wl1, bl1, Wr1, br1, bufB, bufC, N);
    gatv2_agg<2,false><<<(N * 2 + 3) / 4, 256, 0, stream>>>(bufB, bufC, att1, bias1, offsets, counts, edge_src, bufA, N);

    // layer 2: 128 -> 128 (H=2), mean over heads -> 64
    dual_linear_t<128, 256, 256><<<rb, 256, 0, stream>>>(bufA, Wl2, bl2, Wr2, br2, bufB, bufC, N);
    gatv2_agg<2,true ><<<(N + 3) / 4, 256, 0, stream>>>(bufB, bufC, att2, bias2, offsets, counts, edge_src, bufA, N);

    // pooling + output linear
    hipMemsetAsync(gmx,  0, (size_t)B * 64 * 4, stream);
    hipMemsetAsync(gsum, 0, (size_t)B * 64 * 4, stream);
    hipMemsetAsync(gcnt, 0, (size_t)B * 4, stream);
    pool_kernel<<<(N * 64 + 255) / 256, 256, 0, stream>>>(bufA, batch, N, gmx, gsum, gcnt);
    final_linear<<<1, 640, 0, stream>>>(gmx, gsum, gcnt, Wout, bout, (float*)d_out);
}

// Round 4
// 565.945 us; speedup vs baseline: 3.1114x; 1.5819x over previous
//
#include <hip/hip_runtime.h>
#include <hip/hip_bf16.h>
#include <math.h>

#define NEG_SLOPE 0.2f

__device__ __forceinline__ void fma4(float4& a, const float4 w, const float s){
    a.x += w.x * s; a.y += w.y * s; a.z += w.z * s; a.w += w.w * s;
}

// ---------------- CSR build ----------------

__global__ void edge_count(const int* __restrict__ src, const int* __restrict__ dst,
                           int E, int* __restrict__ counts){
    int e = blockIdx.x * blockDim.x + threadIdx.x;
    if (e >= E) return;
    int s = src[e], d = dst[e];
    if (s != d) atomicAdd(&counts[d], 1);
}

__global__ void scan_block(const int* __restrict__ counts, int* __restrict__ offsets,
                           int* __restrict__ blockSums, int N){
    __shared__ int sh[256];
    int t = threadIdx.x;
    int i = blockIdx.x * 256 + t;
    int v = (i < N) ? counts[i] : 0;
    sh[t] = v; __syncthreads();
    for (int off = 1; off < 256; off <<= 1){
        int x = (t >= off) ? sh[t - off] : 0;
        __syncthreads();
        sh[t] += x;
        __syncthreads();
    }
    if (i < N) offsets[i] = sh[t] - v;           // exclusive
    if (t == 255) blockSums[blockIdx.x] = sh[255];
}

__global__ void scan_sums(int* __restrict__ blockSums, int nb){
    __shared__ int sh[256];
    int t = threadIdx.x;
    int v = (t < nb) ? blockSums[t] : 0;
    sh[t] = v; __syncthreads();
    for (int off = 1; off < 256; off <<= 1){
        int x = (t >= off) ? sh[t - off] : 0;
        __syncthreads();
        sh[t] += x;
        __syncthreads();
    }
    if (t < nb) blockSums[t] = sh[t] - v;        // exclusive
}

__global__ void scan_add(int* __restrict__ offsets, const int* __restrict__ blockSums, int N){
    int i = blockIdx.x * 256 + threadIdx.x;
    if (i < N) offsets[i] += blockSums[blockIdx.x];
}

__global__ void copy_int(const int* __restrict__ a, int* __restrict__ b, int N){
    int i = blockIdx.x * blockDim.x + threadIdx.x;
    if (i < N) b[i] = a[i];
}

__global__ void edge_scatter(const int* __restrict__ src, const int* __restrict__ dst,
                             int E, int* __restrict__ cursor, int* __restrict__ edge_src){
    int e = blockIdx.x * blockDim.x + threadIdx.x;
    if (e >= E) return;
    int s = src[e], d = dst[e];
    if (s != d){
        int pos = atomicAdd(&cursor[d], 1);
        edge_src[pos] = s;
    }
}

// ---------------- dual linear (tiled, register-blocked) ----------------
template<int K, int HC2, int NT>
__global__ __launch_bounds__(NT)
void dual_linear_t(const float* __restrict__ in,
                   const float* __restrict__ Wl, const float* __restrict__ bl,
                   const float* __restrict__ Wr, const float* __restrict__ br,
                   float* __restrict__ xl, float* __restrict__ xr, int N){
    constexpr int HC = HC2 / 2;
    constexpr int CG = HC2 / 4;        // col groups of 4
    constexpr int STR = 36;            // LDS stride (floats), 144B = 16B-aligned
    __shared__ __align__(16) float xsT[K * STR];
    const int tid = threadIdx.x;
    const int row0 = blockIdx.x * 32;

    #pragma unroll 4
    for (int r = 0; r < 32; ++r){
        int gr = row0 + r; if (gr > N - 1) gr = N - 1;
        const float* ip = in + (size_t)gr * K;
        for (int k = tid; k < K; k += NT) xsT[k * STR + r] = ip[k];
    }
    __syncthreads();

    const int cg = tid % CG, rg = tid / CG;
    const int c4 = cg * 4, r8 = rg * 8;
    const bool left = c4 < HC;
    const float* Wb = left ? (Wl + c4) : (Wr + (c4 - HC));
    const float* bb = left ? (bl + c4) : (br + (c4 - HC));
    const float4 bv = *(const float4*)bb;
    float4 acc[8];
    #pragma unroll
    for (int r = 0; r < 8; ++r) acc[r] = bv;

    const float* wp = Wb;
    const float* xp = &xsT[r8];
    #pragma unroll 4
    for (int k = 0; k < K; ++k){
        float4 wv = *(const float4*)wp;  wp += HC;
        float4 xa = *(const float4*)xp;
        float4 xb = *(const float4*)(xp + 4);
        xp += STR;
        fma4(acc[0], wv, xa.x); fma4(acc[1], wv, xa.y);
        fma4(acc[2], wv, xa.z); fma4(acc[3], wv, xa.w);
        fma4(acc[4], wv, xb.x); fma4(acc[5], wv, xb.y);
        fma4(acc[6], wv, xb.z); fma4(acc[7], wv, xb.w);
    }

    float* ob = left ? (xl + c4) : (xr + (c4 - HC));
    #pragma unroll
    for (int r = 0; r < 8; ++r){
        int row = row0 + r8 + r;
        if (row < N) *(float4*)&ob[(size_t)row * HC] = acc[r];
    }
}

// ---------------- GATv2 aggregation ----------------
template<int H, bool MEAN>
__global__ __launch_bounds__(256)
void gatv2_agg(const float* __restrict__ xl, const float* __restrict__ xr,
               const float* __restrict__ att, const float* __restrict__ bias,
               const int* __restrict__ offsets, const int* __restrict__ counts,
               const int* __restrict__ edge_src,
               float* __restrict__ hout, int N){
    const int HC = H * 64;
    int wid  = (blockIdx.x * 256 + threadIdx.x) >> 6;
    int lane = threadIdx.x & 63;
    int g = lane >> 4, sl = lane & 15, cb = sl * 4;
    int n, h0, h1;
    if (MEAN){ n = wid; h0 = 0; h1 = H; }
    else     { n = wid / H; h0 = wid - n * H; h1 = h0 + 1; }
    if (n >= N) return;
    const int rs = offsets[n];
    const int total = counts[n] + 1;     // + implicit self loop (virtual idx 0)

    float ox = 0.f, oy = 0.f, oz = 0.f, ow = 0.f;
    for (int h = h0; h < h1; ++h){
        const float4 a4 = *(const float4*)&att[h * 64 + cb];
        const float4 q4 = *(const float4*)&xr[(size_t)n * HC + h * 64 + cb];
        const float* XT = xl + h * 64 + cb;
        float m = -INFINITY, den = 0.f;
        float ax = 0.f, ay = 0.f, az = 0.f, aw = 0.f;
        for (int j = g; j < total; j += 4){
            int s = (j == 0) ? n : edge_src[rs + j - 1];
            float4 xv = *(const float4*)&XT[(size_t)s * HC];
            float t0 = q4.x + xv.x, t1 = q4.y + xv.y;
            float t2 = q4.z + xv.z, t3 = q4.w + xv.w;
            t0 = t0 > 0.f ? t0 : NEG_SLOPE * t0;
            t1 = t1 > 0.f ? t1 : NEG_SLOPE * t1;
            t2 = t2 > 0.f ? t2 : NEG_SLOPE * t2;
            t3 = t3 > 0.f ? t3 : NEG_SLOPE * t3;
            float p = a4.x * t0 + a4.y * t1 + a4.z * t2 + a4.w * t3;
            p += __shfl_xor(p, 1, 64);
            p += __shfl_xor(p, 2, 64);
            p += __shfl_xor(p, 4, 64);
            p += __shfl_xor(p, 8, 64);
            float Mn = fmaxf(m, p);
            float ea = __expf(m - Mn);
            float eb = __expf(p - Mn);
            den = den * ea + eb;
            ax = ax * ea + eb * xv.x; ay = ay * ea + eb * xv.y;
            az = az * ea + eb * xv.z; aw = aw * ea + eb * xv.w;
            m = Mn;
        }
        #pragma unroll
        for (int off = 16; off <= 32; off <<= 1){
            float mo  = __shfl_xor(m,  off, 64);
            float dno = __shfl_xor(den, off, 64);
            float bx = __shfl_xor(ax, off, 64), by = __shfl_xor(ay, off, 64);
            float bz = __shfl_xor(az, off, 64), bw = __shfl_xor(aw, off, 64);
            float Mn = fmaxf(m, mo);
            float sa = (m  == -INFINITY) ? 0.f : __expf(m  - Mn);
            float sb = (mo == -INFINITY) ? 0.f : __expf(mo - Mn);
            den = den * sa + dno * sb;
            ax = ax * sa + bx * sb; ay = ay * sa + by * sb;
            az = az * sa + bz * sb; aw = aw * sa + bw * sb;
            m = Mn;
        }
        float inv = 1.f / den;
        ox += ax * inv; oy += ay * inv; oz += az * inv; ow += aw * inv;
    }
    if (lane < 16){
        float4 o;
        if (MEAN){
            const float s = 1.f / H;
            const float4 bv = *(const float4*)&bias[cb];
            o.x = fmaxf(ox * s + bv.x, 0.f);
            o.y = fmaxf(oy * s + bv.y, 0.f);
            o.z = fmaxf(oz * s + bv.z, 0.f);
            o.w = fmaxf(ow * s + bv.w, 0.f);
            *(float4*)&hout[(size_t)n * 64 + cb] = o;
        } else {
            const float4 bv = *(const float4*)&bias[h0 * 64 + cb];
            o.x = fmaxf(ox + bv.x, 0.f);
            o.y = fmaxf(oy + bv.y, 0.f);
            o.z = fmaxf(oz + bv.z, 0.f);
            o.w = fmaxf(ow + bv.w, 0.f);
            *(float4*)&hout[(size_t)n * HC + h0 * 64 + cb] = o;
        }
    }
}

// ---------------- pooling (run-length local reduce; batch is sorted) ----------------
// Block = 256 nodes, 4 waves; wave w handles nodes n0+w, n0+w+4, ...
// lane = channel. Registers hold (max,sum) for the current graph run; atomics
// fire only on graph transitions (~1 per block) instead of per element.
__global__ __launch_bounds__(256)
void pool_kernel(const float* __restrict__ h, const int* __restrict__ batch,
                 int N, float* __restrict__ gmx, float* __restrict__ gsum,
                 int* __restrict__ gcnt){
    const int lane = threadIdx.x & 63;
    const int w = threadIdx.x >> 6;
    const int n0 = blockIdx.x * 256;
    const int nend = min(n0 + 256, N);
    float rmax = 0.f, rsum = 0.f;
    int curG = -1, cnt = 0;
    for (int n = n0 + w; n < nend; n += 4){
        int g = batch[n];
        float v = h[(size_t)n * 64 + lane];
        if (g != curG){
            if (curG >= 0){
                atomicMax((int*)&gmx[curG * 64 + lane], __float_as_int(rmax));
                atomicAdd(&gsum[curG * 64 + lane], rsum);
                if (lane == 0) atomicAdd(&gcnt[curG], cnt);
            }
            curG = g; rmax = v; rsum = v; cnt = 1;
        } else {
            rmax = fmaxf(rmax, v); rsum += v; ++cnt;
        }
    }
    if (curG >= 0){
        atomicMax((int*)&gmx[curG * 64 + lane], __float_as_int(rmax));
        atomicAdd(&gsum[curG * 64 + lane], rsum);
        if (lane == 0) atomicAdd(&gcnt[curG], cnt);
    }
}

__global__ void final_linear(const float* __restrict__ gmx, const float* __restrict__ gsum,
                             const int* __restrict__ gcnt,
                             const float* __restrict__ Wout, const float* __restrict__ bout,
                             float* __restrict__ out){
    int t = threadIdx.x;             // one block, 640 threads
    if (t >= 640) return;
    int g = t / 10, oc = t % 10;
    float cnt = (float)max(gcnt[g], 1);
    float acc = bout[oc];
    for (int k = 0; k < 64; ++k)  acc += gmx[g * 64 + k] * Wout[k * 10 + oc];
    for (int k = 0; k < 64; ++k)  acc += (gsum[g * 64 + k] / cnt) * Wout[(64 + k) * 10 + oc];
    out[g * 10 + oc] = acc;
}

// ---------------- launch ----------------
extern "C" void kernel_launch(void* const* d_in, const int* in_sizes, int n_in,
                              void* d_out, int out_size, void* d_ws, size_t ws_size,
                              hipStream_t stream){
    const int N = 50000, E = 800000, B = 64;
    const float* x    = (const float*)d_in[0];
    const int*  ei    = (const int*)d_in[1];
    const int*  batch = (const int*)d_in[2];
    const float *Wl0=(const float*)d_in[3],  *bl0=(const float*)d_in[4],
                *Wr0=(const float*)d_in[5],  *br0=(const float*)d_in[6],
                *att0=(const float*)d_in[7], *bias0=(const float*)d_in[8];
    const float *Wl1=(const float*)d_in[9],  *bl1=(const float*)d_in[10],
                *Wr1=(const float*)d_in[11], *br1=(const float*)d_in[12],
                *att1=(const float*)d_in[13],*bias1=(const float*)d_in[14];
    const float *Wl2=(const float*)d_in[15], *bl2=(const float*)d_in[16],
                *Wr2=(const float*)d_in[17], *br2=(const float*)d_in[18],
                *att2=(const float*)d_in[19],*bias2=(const float*)d_in[20];
    const float *Wout=(const float*)d_in[21],*bout=(const float*)d_in[22];

    const int* srcA = ei;
    const int* dstA = ei + E;

    char* p = (char*)d_ws;
    auto alloc = [&](size_t bytes)->void*{ void* r = (void*)p; p += (bytes + 255) & ~(size_t)255; return r; };
    float* bufA   = (float*)alloc((size_t)N * 192 * 4);
    float* bufB   = (float*)alloc((size_t)N * 192 * 4);
    float* bufC   = (float*)alloc((size_t)N * 192 * 4);
    int* counts   = (int*)alloc((size_t)N * 4);
    int* offsets  = (int*)alloc((size_t)N * 4);
    int* cursor   = (int*)alloc((size_t)N * 4);
    int* blockSums= (int*)alloc(256 * 4);
    int* edge_src = (int*)alloc((size_t)E * 4);
    float* gmx    = (float*)alloc((size_t)B * 64 * 4);
    float* gsum   = (float*)alloc((size_t)B * 64 * 4);
    int* gcnt     = (int*)alloc((size_t)B * 4);

    // CSR build (reused by all 3 layers)
    hipMemsetAsync(counts, 0, (size_t)N * 4, stream);
    int eb = (E + 255) / 256;
    int nb = (N + 255) / 256;
    edge_count<<<eb, 256, 0, stream>>>(srcA, dstA, E, counts);
    scan_block<<<nb, 256, 0, stream>>>(counts, offsets, blockSums, N);
    scan_sums<<<1, 256, 0, stream>>>(blockSums, nb);
    scan_add<<<nb, 256, 0, stream>>>(offsets, blockSums, N);
    copy_int<<<nb, 256, 0, stream>>>(offsets, cursor, N);
    edge_scatter<<<eb, 256, 0, stream>>>(srcA, dstA, E, cursor, edge_src);

    const int rb = (N + 31) / 32;   // row-tile blocks for linears

    // layer 0: 32 -> 192 (H=3, C=64), concat
    dual_linear_t<32, 384, 384><<<rb, 384, 0, stream>>>(x, Wl0, bl0, Wr0, br0, bufB, bufC, N);
    gatv2_agg<3,false><<<(N * 3 + 3) / 4, 256, 0, stream>>>(bufB, bufC, att0, bias0, offsets, counts, edge_src, bufA, N);

    // layer 1: 192 -> 128 (H=2), concat
    dual_linear_t<192, 256, 256><<<rb, 256, 0, stream>>>(bufA, Wl1, bl1, Wr1, br1, bufB, bufC, N);
    gatv2_agg<2,false><<<(N * 2 + 3) / 4, 256, 0, stream>>>(bufB, bufC, att1, bias1, offsets, counts, edge_src, bufA, N);

    // layer 2: 128 -> 128 (H=2), mean over heads -> 64
    dual_linear_t<128, 256, 256><<<rb, 256, 0, stream>>>(bufA, Wl2, bl2, Wr2, br2, bufB, bufC, N);
    gatv2_agg<2,true ><<<(N + 3) / 4, 256, 0, stream>>>(bufB, bufC, att2, bias2, offsets, counts, edge_src, bufA, N);

    // pooling + output linear
    hipMemsetAsync(gmx,  0, (size_t)B * 64 * 4, stream);
    hipMemsetAsync(gsum, 0, (size_t)B * 64 * 4, stream);
    hipMemsetAsync(gcnt, 0, (size_t)B * 4, stream);
    pool_kernel<<<(N + 255) / 256, 256, 0, stream>>>(bufA, batch, N, gmx, gsum, gcnt);
    final_linear<<<1, 640, 0, stream>>>(gmx, gsum, gcnt, Wout, bout, (float*)d_out);
}